// Round 17
// baseline (171.291 us; speedup 1.0000x reference)
//
#include <hip/hip_runtime.h>
#include <hip/hip_bf16.h>

// DiffAttn forward, MI355X/gfx950. bf16 MFMA everywhere, f32 softmax/LN.
// ws layout (u16 units, SZ = 2048*2048):
//   xb, Wqt, Wkt, Wvt, Wot, Qb, Kb, Vtb, Mb  -> 9*8MB = 72MB

typedef unsigned short u16;
typedef __attribute__((ext_vector_type(4))) float f32x4;
typedef __attribute__((ext_vector_type(8))) short bf16x8;

#define LAMBDA_INIT  0.7836057665317954f
#define ONE_MINUS_LI 0.2163942334682046f
// Q scale = hd^-0.5 * log2(e): QK^T lands pre-scaled for exp2-based softmax
#define QSCALE 0.18033688011112042f

// raw v_exp_f32 (exp2 semantics); avoids glibc __exp2f macro collision
#define EXP2F(x) __builtin_amdgcn_exp2f(x)

__device__ __forceinline__ u16 f2bf(float f) {
    union { float f; unsigned u; } v; v.f = f;
    unsigned r = v.u + 0x7FFFu + ((v.u >> 16) & 1u);   // RNE
    return (u16)(r >> 16);
}

// packed f32x2 -> bf16x2 (compiler emits v_cvt_pk_bf16_f32)
__device__ __forceinline__ unsigned pkbf(float a, float b) {
    union { __hip_bfloat162 h; unsigned u; } c;
    c.h = __float22bfloat162_rn(make_float2(a, b));
    return c.u;
}

__device__ __forceinline__ void gld_lds16(const u16* g, u16* l) {
    __builtin_amdgcn_global_load_lds((const __attribute__((address_space(1))) void*)g,
                                     (__attribute__((address_space(3))) void*)l, 16, 0, 0);
}

// ---------------- prep: z<4 -> transpose+cast W_z; z==4 -> cast x ----------------
__global__ void prep_inputs(const float* __restrict__ x, const float* __restrict__ W0,
                            const float* __restrict__ W1, const float* __restrict__ W2,
                            const float* __restrict__ W3,
                            u16* __restrict__ xb, u16* __restrict__ O0, u16* __restrict__ O1,
                            u16* __restrict__ O2, u16* __restrict__ O3) {
    __shared__ float tile[64][65];
    const int z = blockIdx.z;
    const int c0 = blockIdx.x * 64, r0 = blockIdx.y * 64;
    const int t = threadIdx.x;
    const int lr = t >> 2, lc = (t & 3) << 4;

    if (z == 4) {
        const float* src = x + (size_t)(r0 + lr) * 2048 + c0 + lc;
        uint ou[8];
#pragma unroll
        for (int jj = 0; jj < 4; jj++) {
            float4 v = *(const float4*)(src + 4 * jj);
            ou[2 * jj + 0] = pkbf(v.x, v.y);
            ou[2 * jj + 1] = pkbf(v.z, v.w);
        }
        u16* dst = xb + (size_t)(r0 + lr) * 2048 + c0 + lc;
        *(uint4*)(dst) = *(uint4*)&ou[0];
        *(uint4*)(dst + 8) = *(uint4*)&ou[4];
        return;
    }

    const float* W = z == 0 ? W0 : z == 1 ? W1 : z == 2 ? W2 : W3;
    u16* Wt = z == 0 ? O0 : z == 1 ? O1 : z == 2 ? O2 : O3;
#pragma unroll
    for (int jj = 0; jj < 4; jj++) {
        float4 v = *(const float4*)(W + (size_t)(r0 + lr) * 2048 + c0 + lc + 4 * jj);
        tile[lr][lc + 4 * jj + 0] = v.x;
        tile[lr][lc + 4 * jj + 1] = v.y;
        tile[lr][lc + 4 * jj + 2] = v.z;
        tile[lr][lc + 4 * jj + 3] = v.w;
    }
    __syncthreads();
    const int oc = t >> 2, op = (t & 3) << 4;
    uint ou[8];
#pragma unroll
    for (int k = 0; k < 8; k++)
        ou[k] = pkbf(tile[op + 2 * k][oc], tile[op + 2 * k + 1][oc]);
    u16* dst = Wt + (size_t)(c0 + oc) * 2048 + r0 + op;
    *(uint4*)(dst) = *(uint4*)&ou[0];
    *(uint4*)(dst + 8) = *(uint4*)&ou[4];
}

// ---------------- QKV GEMM: 256x256 tile, BK=64, 8 waves, 8-phase counted-vmcnt schedule ----------------
// T3+T4+T2 (R15, conflicts=0). Size-limited plateau at N=2048 (770 TF, 192 blocks / 256 CUs).
__global__ __launch_bounds__(512, 2) void gemm_qkv(const u16* __restrict__ xb,
                                                   const u16* __restrict__ Wqt, const u16* __restrict__ Wkt,
                                                   const u16* __restrict__ Wvt,
                                                   u16* __restrict__ Qb, u16* __restrict__ Kb,
                                                   u16* __restrict__ Vtb) {
    __shared__ __align__(16) u16 lds[2][2][2][256 * 32];   // [buf][type A/B][kk][row*32+col] = 128KB
    const int tid = threadIdx.x;
    const int lane = tid & 63, wv = tid >> 6;
    const int wm = wv >> 2, wn = wv & 3;           // 2M x 4N waves
    const int q16 = lane & 15, g = lane >> 4;

    const int id = blockIdx.x;
    const int ord = (id & 7) * 24 + (id >> 3);     // bijective XCD chunking (192 % 8 == 0)
    const int which = ord / 64, r = ord % 64;
    const int m0 = (r & 7) * 256, n0 = (r >> 3) * 256;
    const u16 *Ap, *Bp; u16* Cp; float sc;
    if (which == 0)      { Ap = xb;  Bp = Wqt; Cp = Qb;  sc = QSCALE; }
    else if (which == 1) { Ap = xb;  Bp = Wkt; Cp = Kb;  sc = 1.f; }
    else                 { Ap = Wvt; Bp = xb;  Cp = Vtb; sc = 1.f; }

#define STAGE_HALF(buf, type, kk, kb)                                                  \
    {                                                                                  \
        const u16* _src = (type) == 0 ? Ap : Bp;                                       \
        const int _b0 = (type) == 0 ? m0 : n0;                                         \
        u16* _dst = &lds[buf][type][kk][0];                                            \
        _Pragma("unroll") for (int _i = 0; _i < 2; _i++) {                             \
            int _s = _i * 512 + tid;                                                   \
            int _row = _s >> 2, _gr = _s & 3;                                          \
            int _sg = (_gr ^ (_row >> 1)) & 3;                                         \
            gld_lds16(_src + (size_t)(_b0 + _row) * 2048 + (kb) + (kk) * 32 + _sg * 8, \
                      _dst + _s * 8);                                                  \
        }                                                                              \
    }

    const f32x4 fzero = {0.f, 0.f, 0.f, 0.f};
    f32x4 acc[8][4];
#pragma unroll
    for (int m = 0; m < 8; m++)
#pragma unroll
        for (int n = 0; n < 4; n++) acc[m][n] = fzero;

    STAGE_HALF(0, 0, 0, 0);
    STAGE_HALF(0, 1, 0, 0);
    STAGE_HALF(0, 0, 1, 0);
    STAGE_HALF(0, 1, 1, 0);
    asm volatile("s_waitcnt vmcnt(4)" ::: "memory");
    __builtin_amdgcn_s_barrier();

    const int NT = 32;   // 2048 / 64
    for (int t = 0; t < NT; t++) {
        const int buf = t & 1, nbuf = buf ^ 1;
        const int kbn = (t + 1) * 64;
        const bool more = (t + 1 < NT);
        bf16x8 af[8];
#pragma unroll
        for (int p = 0; p < 4; p++) {
            const int kk = p >> 1, nh = p & 1;
            if (nh == 0) {
#pragma unroll
                for (int m = 0; m < 8; m++) {
                    int row = wm * 128 + m * 16 + q16;
                    af[m] = *(const bf16x8*)(&lds[buf][0][kk][row * 32 + 8 * ((g ^ (row >> 1)) & 3)]);
                }
            }
            bf16x8 bf0, bf1;
            {
                int rb0 = wn * 64 + (2 * nh + 0) * 16 + q16;
                int rb1 = wn * 64 + (2 * nh + 1) * 16 + q16;
                bf0 = *(const bf16x8*)(&lds[buf][1][kk][rb0 * 32 + 8 * ((g ^ (rb0 >> 1)) & 3)]);
                bf1 = *(const bf16x8*)(&lds[buf][1][kk][rb1 * 32 + 8 * ((g ^ (rb1 >> 1)) & 3)]);
            }
            if (more) {
                if (p == 0)      STAGE_HALF(nbuf, 0, 0, kbn)
                else if (p == 1) STAGE_HALF(nbuf, 1, 0, kbn)
                else if (p == 2) STAGE_HALF(nbuf, 0, 1, kbn)
                else             STAGE_HALF(nbuf, 1, 1, kbn)
            }
            __builtin_amdgcn_s_barrier();
            asm volatile("s_waitcnt lgkmcnt(0)" ::: "memory");
            __builtin_amdgcn_s_setprio(1);
#pragma unroll
            for (int m = 0; m < 8; m++) {
                acc[m][2 * nh + 0] = __builtin_amdgcn_mfma_f32_16x16x32_bf16(af[m], bf0, acc[m][2 * nh + 0], 0, 0, 0);
                acc[m][2 * nh + 1] = __builtin_amdgcn_mfma_f32_16x16x32_bf16(af[m], bf1, acc[m][2 * nh + 1], 0, 0, 0);
            }
            __builtin_amdgcn_s_setprio(0);
            if (p == 1) {
                if (more) asm volatile("s_waitcnt vmcnt(4)" ::: "memory");
                else      asm volatile("s_waitcnt vmcnt(0)" ::: "memory");
            } else if (p == 3) {
                asm volatile("s_waitcnt vmcnt(4)" ::: "memory");
            }
            __builtin_amdgcn_s_barrier();
        }
    }
#undef STAGE_HALF

#pragma unroll
    for (int m = 0; m < 8; m++)
#pragma unroll
        for (int n = 0; n < 4; n++) {
            int row = m0 + wm * 128 + m * 16 + 4 * g;
            int col = n0 + wn * 64 + n * 16 + q16;
#pragma unroll
            for (int rr = 0; rr < 4; rr++)
                Cp[(size_t)(row + rr) * 2048 + col] = f2bf(acc[m][n][rr] * sc);
        }
}

// ---------------- GEMM core (BK=64, 128x64): proven R8 core, for the f32-output projection ----------------
__device__ __forceinline__ void gemm_core64(const u16* __restrict__ A, const u16* __restrict__ B,
                                            float* __restrict__ Cout, float scale, int m0, int n0) {
    __shared__ __align__(16) u16 As[2][128 * 64];
    __shared__ __align__(16) u16 Bs[2][64 * 64];
    const int tid = threadIdx.x;
    const int lane = tid & 63, w = tid >> 6;
    const int q16 = lane & 15, g = lane >> 4;
    const int sw = q16 & 7;
    const f32x4 fzero = {0.f, 0.f, 0.f, 0.f};
    f32x4 acc[2][4];
#pragma unroll
    for (int m = 0; m < 2; m++)
#pragma unroll
        for (int n = 0; n < 4; n++) acc[m][n] = fzero;

#define STG64(buf, kb)                                                               \
    {                                                                                \
        _Pragma("unroll") for (int p = 0; p < 4; p++) {                              \
            int s = p * 256 + tid;  /* A: 1024 granules */                           \
            int row = s >> 3, sg = (s ^ row) & 7;                                    \
            gld_lds16(A + (size_t)(m0 + row) * 2048 + (kb) + sg * 8, As[buf] + s * 8); \
        }                                                                            \
        _Pragma("unroll") for (int p = 0; p < 2; p++) {                              \
            int s = p * 256 + tid;  /* B: 512 granules */                            \
            int row = s >> 3, sg = (s ^ row) & 7;                                    \
            gld_lds16(B + (size_t)(n0 + row) * 2048 + (kb) + sg * 8, Bs[buf] + s * 8); \
        }                                                                            \
    }

    STG64(0, 0);
    int cur = 0;
    for (int kb = 0; kb < 2048; kb += 64) {
        if (kb + 64 < 2048) {
            STG64(cur ^ 1, kb + 64);
            asm volatile("s_waitcnt vmcnt(6)" ::: "memory");
        } else {
            asm volatile("s_waitcnt vmcnt(0)" ::: "memory");
        }
        __builtin_amdgcn_s_barrier();
        bf16x8 af[2][2], bfr[4][2];
#pragma unroll
        for (int m = 0; m < 2; m++) {
            const u16* ar = As[cur] + (w * 32 + m * 16 + q16) * 64;
            af[m][0] = *(const bf16x8*)(ar + 8 * (g ^ sw));
            af[m][1] = *(const bf16x8*)(ar + 8 * ((4 + g) ^ sw));
        }
#pragma unroll
        for (int n = 0; n < 4; n++) {
            const u16* br = Bs[cur] + (n * 16 + q16) * 64;
            bfr[n][0] = *(const bf16x8*)(br + 8 * (g ^ sw));
            bfr[n][1] = *(const bf16x8*)(br + 8 * ((4 + g) ^ sw));
        }
        __builtin_amdgcn_s_setprio(1);
#pragma unroll
        for (int m = 0; m < 2; m++)
#pragma unroll
            for (int n = 0; n < 4; n++) {
                acc[m][n] = __builtin_amdgcn_mfma_f32_16x16x32_bf16(af[m][0], bfr[n][0], acc[m][n], 0, 0, 0);
                acc[m][n] = __builtin_amdgcn_mfma_f32_16x16x32_bf16(af[m][1], bfr[n][1], acc[m][n], 0, 0, 0);
            }
        __builtin_amdgcn_s_setprio(0);
        asm volatile("s_waitcnt lgkmcnt(0)" ::: "memory");
        __builtin_amdgcn_s_barrier();
        cur ^= 1;
    }
#pragma unroll
    for (int m = 0; m < 2; m++)
#pragma unroll
        for (int n = 0; n < 4; n++) {
            int row = m0 + w * 32 + m * 16 + 4 * g;
            int col = n0 + n * 16 + q16;
#pragma unroll
            for (int r = 0; r < 4; r++)
                Cout[(size_t)(row + r) * 2048 + col] = acc[m][n][r] * scale;
        }
#undef STG64
}

// final projection: 512 blocks (128x64 tiles)
__global__ __launch_bounds__(256, 3) void gemm_out(const u16* __restrict__ Mb, const u16* __restrict__ Wot,
                                                   float* __restrict__ out) {
    const int id = blockIdx.x;
    const int ord = (id & 7) * 64 + (id >> 3);
    const int m0 = (ord & 15) * 128, n0 = (ord >> 4) * 64;
    gemm_core64(Mb, Wot, out, 1.f, m0, n0);
}

// ---------------- fused dual-stream causal flash attention + diff + subLN + scatter to M ----------------
// grid 512 1D. Per-XCD balanced block remap ((A,33-A) size pairs -> 33 tile-iters per CU).
// No-max softmax (exp2 raw, bounded). K tile full 4-bit granule XOR swizzle (conflict-free kf reads).
// T14 V-hoist; staging issued AFTER QK^T (prev-tile loads get full-iteration cover -> top
// vmcnt(0) is free); lambda via wave-parallel dot (loads at entry, butterfly in epilogue);
// last-iteration trailing sync elided.
__global__ __launch_bounds__(256, 2) void diff_attn(const u16* __restrict__ Qg, const u16* __restrict__ Kg,
                                                    const u16* __restrict__ Vg, u16* __restrict__ Mg,
                                                    const float* __restrict__ lq1, const float* __restrict__ lk1,
                                                    const float* __restrict__ lq2, const float* __restrict__ lk2) {
    __shared__ __align__(16) u16 smem[40960];   // 80 KB -> 2 blocks/CU
    const int tid = threadIdx.x;
    const int lane = tid & 63, w = tid >> 6;
    const int q16 = lane & 15, g = lane >> 4;
    const int sw = q16 & 7;
    const int id = blockIdx.x;
    // balanced remap: XCD xcd, pair p, parity o. A(p) = 32-p (p<16) else p-15.
    const int xcd = id & 7, jj = id >> 3;
    const int p = jj >> 1, o = jj & 1;
    const int A = (p < 16) ? (32 - p) : (p - 15);
    const int s = o ? (33 - A) : A;   // tile count for this block, 1..32
    const int qi = s - 1;
    const int h = (xcd << 1) | o;
    const int q0 = qi * 64;
    const int qg = q0 + 16 * w + q16;

    // lambda partials: coalesced per-lane loads now, butterfly-reduced in the epilogue
    float la1 = lq1[lane] * lk1[lane];
    float la2 = lq2[lane] * lk2[lane];

    u16* Kb0 = smem;
    u16* Vb0 = smem + 8192;
    u16* Kb1 = smem + 16384;
    u16* Vb1 = smem + 24576;
    u16* Pw = smem + 32768 + w * 2048;  // [2 streams][16 q][64 k]

    bf16x8 qf[2][2];
#pragma unroll
    for (int st = 0; st < 2; st++)
#pragma unroll
        for (int db = 0; db < 2; db++)
            qf[st][db] = *(const bf16x8*)(Qg + (size_t)qg * 2048 + 128 * h + 64 * st + 32 * db + 8 * g);

// K: LDS slot gc (of row) holds global granule gc^(row&15); read granule j at slot j^(row&15)
#define STAGE_K(dst, kb)                                                         \
    {                                                                            \
        _Pragma("unroll") for (int p2 = 0; p2 < 4; p2++) {                       \
            int s2 = p2 * 256 + tid;                                             \
            int row = s2 >> 4, gc = s2 & 15;                                     \
            int sg = (gc ^ row) & 15;                                            \
            gld_lds16(Kg + (size_t)((kb) + row) * 2048 + 128 * h + sg * 8, (dst) + s2 * 8); \
        }                                                                        \
    }
#define STAGE_V(dst, kb)                                                         \
    {                                                                            \
        _Pragma("unroll") for (int p2 = 0; p2 < 4; p2++) {                       \
            int s2 = p2 * 256 + tid;                                             \
            int row = s2 >> 3, sg = (s2 ^ row) & 7;                              \
            gld_lds16(Vg + (size_t)(128 * h + row) * 2048 + (kb) + sg * 8, (dst) + s2 * 8); \
        }                                                                        \
    }

    const f32x4 fzero = {0.f, 0.f, 0.f, 0.f};
    f32x4 Oacc[2][8];
#pragma unroll
    for (int st = 0; st < 2; st++)
#pragma unroll
        for (int dt = 0; dt < 8; dt++) Oacc[st][dt] = fzero;
    float den[2] = {0.f, 0.f};   // per-lane partial denominators; reduced in epilogue

    const int nt = qi + 1;
    STAGE_K(Kb0, 0);
    STAGE_V(Vb0, 0);
    int cur = 0;
    for (int t = 0; t < nt; t++) {
        const int kb = t * 64;
        const u16* Ks = cur ? Kb1 : Kb0;
        const u16* Vs = cur ? Vb1 : Vb0;
        const bool more = (t + 1 < nt);
        // prev-tile staging had a full iteration of cover -> this drain is ~free
        asm volatile("s_waitcnt vmcnt(0)" ::: "memory");
        __builtin_amdgcn_s_barrier();

        // T14: issue ALL V-fragment reads now; they retire under QK^T + softmax.
        bf16x8 vfr[2][8];
#pragma unroll
        for (int kh = 0; kh < 2; kh++)
#pragma unroll
            for (int dt = 0; dt < 8; dt++)
                vfr[kh][dt] = *(const bf16x8*)(Vs + (dt * 16 + q16) * 64 + 8 * ((kh * 4 + g) ^ sw));

        // QK^T (S^T): D[k][q], both streams; K slots XOR-swizzled by q16
        f32x4 sc[2][4];
        __builtin_amdgcn_s_setprio(1);
#pragma unroll
        for (int st = 0; st < 2; st++)
#pragma unroll
            for (int kt = 0; kt < 4; kt++) {
                const u16* kr = Ks + (kt * 16 + q16) * 128;
                bf16x8 kf0 = *(const bf16x8*)(kr + 8 * ((st * 8 + g) ^ q16));
                bf16x8 kf1 = *(const bf16x8*)(kr + 8 * ((st * 8 + 4 + g) ^ q16));
                f32x4 a = __builtin_amdgcn_mfma_f32_16x16x32_bf16(kf0, qf[st][0], fzero, 0, 0, 0);
                a = __builtin_amdgcn_mfma_f32_16x16x32_bf16(kf1, qf[st][1], a, 0, 0, 0);
                sc[st][kt] = a;
            }
        __builtin_amdgcn_s_setprio(0);

        // stage next tile (into the other buffer) AFTER QK^T issue — published at next top
        if (more) {
            STAGE_K(cur ? Kb0 : Kb1, kb + 64);
            STAGE_V(cur ? Vb0 : Vb1, kb + 64);
        }

        const bool last = !more;
        // no-max softmax: P = exp2(S) raw (bounded), mask via select-to-zero on diag tile
#pragma unroll
        for (int st = 0; st < 2; st++) {
            u16* Pst = Pw + st * 1024;
            float dl = 0.f;
#pragma unroll
            for (int kt = 0; kt < 4; kt++) {
                float p0 = EXP2F(sc[st][kt][0]);
                float p1 = EXP2F(sc[st][kt][1]);
                float p2 = EXP2F(sc[st][kt][2]);
                float p3 = EXP2F(sc[st][kt][3]);
                if (last) {
                    const int kgi = kb + kt * 16 + 4 * g;
                    p0 = (kgi + 0 <= qg) ? p0 : 0.f;
                    p1 = (kgi + 1 <= qg) ? p1 : 0.f;
                    p2 = (kgi + 2 <= qg) ? p2 : 0.f;
                    p3 = (kgi + 3 <= qg) ? p3 : 0.f;
                }
                dl += (p0 + p1) + (p2 + p3);
                uint2 pr;
                pr.x = pkbf(p0, p1);
                pr.y = pkbf(p2, p3);
                *(uint2*)(Pst + q16 * 64 + ((kt * 16 + 4 * g) ^ (8 * sw))) = pr;
            }
            den[st] += dl;
        }

        // PV: O^T = V^T x P^T ; V fragments already in registers
        bf16x8 pf[2][2];
#pragma unroll
        for (int st = 0; st < 2; st++)
#pragma unroll
            for (int kh = 0; kh < 2; kh++)
                pf[st][kh] = *(const bf16x8*)(Pw + st * 1024 + q16 * 64 + ((kh * 32 + 8 * g) ^ (8 * sw)));
        __builtin_amdgcn_s_setprio(1);
#pragma unroll
        for (int kh = 0; kh < 2; kh++)
#pragma unroll
            for (int dt = 0; dt < 8; dt++) {
                Oacc[0][dt] = __builtin_amdgcn_mfma_f32_16x16x32_bf16(vfr[kh][dt], pf[0][kh], Oacc[0][dt], 0, 0, 0);
                Oacc[1][dt] = __builtin_amdgcn_mfma_f32_16x16x32_bf16(vfr[kh][dt], pf[1][kh], Oacc[1][dt], 0, 0, 0);
            }
        __builtin_amdgcn_s_setprio(0);
        if (more) {
            // all waves must finish reading buf[cur] before next iter's staging overwrites it
            asm volatile("s_waitcnt lgkmcnt(0)" ::: "memory");
            __builtin_amdgcn_s_barrier();
        }
        cur ^= 1;
    }
#undef STAGE_K
#undef STAGE_V

    // lambda: butterfly-reduce the per-lane partials across all 64 lanes
#pragma unroll
    for (int m = 1; m < 64; m <<= 1) {
        la1 += __shfl_xor(la1, m);
        la2 += __shfl_xor(la2, m);
    }
    const float lam = expf(la1) - expf(la2) + LAMBDA_INIT;

    // epilogue: reduce denominators across the 4-lane q-group, diff, LN over 128 dims, M write
    float d0 = den[0], d1 = den[1];
    d0 += __shfl_xor(d0, 16); d0 += __shfl_xor(d0, 32);
    d1 += __shfl_xor(d1, 16); d1 += __shfl_xor(d1, 32);
    const float i1 = 1.f / d0;
    const float i2 = lam / d1;
    float S1 = 0.f, S2 = 0.f;
#pragma unroll
    for (int dt = 0; dt < 8; dt++)
#pragma unroll
        for (int r = 0; r < 4; r++) {
            float v = Oacc[0][dt][r] * i1 - Oacc[1][dt][r] * i2;
            S1 += v; S2 += v * v;
        }
    S1 += __shfl_xor(S1, 16); S1 += __shfl_xor(S1, 32);
    S2 += __shfl_xor(S2, 16); S2 += __shfl_xor(S2, 32);
    const float mu = S1 * (1.f / 128.f);
    const float var = S2 * (1.f / 128.f) - mu * mu;
    const float rs = rsqrtf(var + 1e-5f) * ONE_MINUS_LI;

    const int R = h * 128 + (q0 >> 4) + w;  // same for whole wave
    u16* drow = Mg + (size_t)R * 2048 + q16 * 128;
#pragma unroll
    for (int dt = 0; dt < 8; dt++) {
        float v0 = (Oacc[0][dt][0] * i1 - Oacc[1][dt][0] * i2 - mu) * rs;
        float v1 = (Oacc[0][dt][1] * i1 - Oacc[1][dt][1] * i2 - mu) * rs;
        float v2 = (Oacc[0][dt][2] * i1 - Oacc[1][dt][2] * i2 - mu) * rs;
        float v3 = (Oacc[0][dt][3] * i1 - Oacc[1][dt][3] * i2 - mu) * rs;
        uint2 oo;
        oo.x = pkbf(v0, v1);
        oo.y = pkbf(v2, v3);
        *(uint2*)(drow + dt * 16 + 4 * g) = oo;
    }
}

extern "C" void kernel_launch(void* const* d_in, const int* in_sizes, int n_in,
                              void* d_out, int out_size, void* d_ws, size_t ws_size,
                              hipStream_t stream) {
    (void)in_sizes; (void)n_in; (void)out_size; (void)ws_size;
    const float* x = (const float*)d_in[0];
    const float* Wq = (const float*)d_in[1];
    const float* Wk = (const float*)d_in[2];
    const float* Wv = (const float*)d_in[3];
    const float* Wo = (const float*)d_in[4];
    const float* lq1 = (const float*)d_in[5];
    const float* lk1 = (const float*)d_in[6];
    const float* lq2 = (const float*)d_in[7];
    const float* lk2 = (const float*)d_in[8];

    u16* ws = (u16*)d_ws;
    const size_t SZ = 2048u * 2048u;
    u16* xb = ws;
    u16* Wqt = ws + SZ;
    u16* Wkt = ws + 2 * SZ;
    u16* Wvt = ws + 3 * SZ;
    u16* Wot = ws + 4 * SZ;
    u16* Qb = ws + 5 * SZ;
    u16* Kb = ws + 6 * SZ;
    u16* Vtb = ws + 7 * SZ;
    u16* Mb = ws + 8 * SZ;

    prep_inputs<<<dim3(32, 32, 5), 256, 0, stream>>>(x, Wq, Wk, Wv, Wo, xb, Wqt, Wkt, Wvt, Wot);

    gemm_qkv<<<192, 512, 0, stream>>>(xb, Wqt, Wkt, Wvt, Qb, Kb, Vtb);

    diff_attn<<<512, 256, 0, stream>>>(Qb, Kb, Vtb, Mb, lq1, lk1, lq2, lk2);

    gemm_out<<<512, 256, 0, stream>>>(Mb, Wot, (float*)d_out);
}

// Round 18
// 156.821 us; speedup vs baseline: 1.0923x; 1.0923x over previous
//
#include <hip/hip_runtime.h>
#include <hip/hip_bf16.h>

// DiffAttn forward, MI355X/gfx950. bf16 MFMA everywhere, f32 softmax/LN.
// ws layout (u16 units, SZ = 2048*2048):
//   xb, Wqt, Wkt, Wvt, Wot, Qb, Kb, Vtb, Mb  -> 9*8MB = 72MB

typedef unsigned short u16;
typedef __attribute__((ext_vector_type(4))) float f32x4;
typedef __attribute__((ext_vector_type(8))) short bf16x8;

#define LAMBDA_INIT  0.7836057665317954f
#define ONE_MINUS_LI 0.2163942334682046f
// Q scale = hd^-0.5 * log2(e): QK^T lands pre-scaled for exp2-based softmax
#define QSCALE 0.18033688011112042f

// raw v_exp_f32 (exp2 semantics); avoids glibc __exp2f macro collision
#define EXP2F(x) __builtin_amdgcn_exp2f(x)

__device__ __forceinline__ u16 f2bf(float f) {
    union { float f; unsigned u; } v; v.f = f;
    unsigned r = v.u + 0x7FFFu + ((v.u >> 16) & 1u);   // RNE
    return (u16)(r >> 16);
}

// packed f32x2 -> bf16x2 (compiler emits v_cvt_pk_bf16_f32)
__device__ __forceinline__ unsigned pkbf(float a, float b) {
    union { __hip_bfloat162 h; unsigned u; } c;
    c.h = __float22bfloat162_rn(make_float2(a, b));
    return c.u;
}

__device__ __forceinline__ void gld_lds16(const u16* g, u16* l) {
    __builtin_amdgcn_global_load_lds((const __attribute__((address_space(1))) void*)g,
                                     (__attribute__((address_space(3))) void*)l, 16, 0, 0);
}

// ---------------- prep: z<4 -> transpose+cast W_z; z==4 -> cast x ----------------
__global__ void prep_inputs(const float* __restrict__ x, const float* __restrict__ W0,
                            const float* __restrict__ W1, const float* __restrict__ W2,
                            const float* __restrict__ W3,
                            u16* __restrict__ xb, u16* __restrict__ O0, u16* __restrict__ O1,
                            u16* __restrict__ O2, u16* __restrict__ O3) {
    __shared__ float tile[64][65];
    const int z = blockIdx.z;
    const int c0 = blockIdx.x * 64, r0 = blockIdx.y * 64;
    const int t = threadIdx.x;
    const int lr = t >> 2, lc = (t & 3) << 4;

    if (z == 4) {
        const float* src = x + (size_t)(r0 + lr) * 2048 + c0 + lc;
        uint ou[8];
#pragma unroll
        for (int jj = 0; jj < 4; jj++) {
            float4 v = *(const float4*)(src + 4 * jj);
            ou[2 * jj + 0] = pkbf(v.x, v.y);
            ou[2 * jj + 1] = pkbf(v.z, v.w);
        }
        u16* dst = xb + (size_t)(r0 + lr) * 2048 + c0 + lc;
        *(uint4*)(dst) = *(uint4*)&ou[0];
        *(uint4*)(dst + 8) = *(uint4*)&ou[4];
        return;
    }

    const float* W = z == 0 ? W0 : z == 1 ? W1 : z == 2 ? W2 : W3;
    u16* Wt = z == 0 ? O0 : z == 1 ? O1 : z == 2 ? O2 : O3;
#pragma unroll
    for (int jj = 0; jj < 4; jj++) {
        float4 v = *(const float4*)(W + (size_t)(r0 + lr) * 2048 + c0 + lc + 4 * jj);
        tile[lr][lc + 4 * jj + 0] = v.x;
        tile[lr][lc + 4 * jj + 1] = v.y;
        tile[lr][lc + 4 * jj + 2] = v.z;
        tile[lr][lc + 4 * jj + 3] = v.w;
    }
    __syncthreads();
    const int oc = t >> 2, op = (t & 3) << 4;
    uint ou[8];
#pragma unroll
    for (int k = 0; k < 8; k++)
        ou[k] = pkbf(tile[op + 2 * k][oc], tile[op + 2 * k + 1][oc]);
    u16* dst = Wt + (size_t)(c0 + oc) * 2048 + r0 + op;
    *(uint4*)(dst) = *(uint4*)&ou[0];
    *(uint4*)(dst + 8) = *(uint4*)&ou[4];
}

// ---------------- QKV GEMM: 256x256 tile, BK=64, 8 waves, 8-phase counted-vmcnt schedule ----------------
// T3+T4+T2 (R15, conflicts=0). Size-limited plateau at N=2048 (770 TF, 192 blocks / 256 CUs).
__global__ __launch_bounds__(512, 2) void gemm_qkv(const u16* __restrict__ xb,
                                                   const u16* __restrict__ Wqt, const u16* __restrict__ Wkt,
                                                   const u16* __restrict__ Wvt,
                                                   u16* __restrict__ Qb, u16* __restrict__ Kb,
                                                   u16* __restrict__ Vtb) {
    __shared__ __align__(16) u16 lds[2][2][2][256 * 32];   // [buf][type A/B][kk][row*32+col] = 128KB
    const int tid = threadIdx.x;
    const int lane = tid & 63, wv = tid >> 6;
    const int wm = wv >> 2, wn = wv & 3;           // 2M x 4N waves
    const int q16 = lane & 15, g = lane >> 4;

    const int id = blockIdx.x;
    const int ord = (id & 7) * 24 + (id >> 3);     // bijective XCD chunking (192 % 8 == 0)
    const int which = ord / 64, r = ord % 64;
    const int m0 = (r & 7) * 256, n0 = (r >> 3) * 256;
    const u16 *Ap, *Bp; u16* Cp; float sc;
    if (which == 0)      { Ap = xb;  Bp = Wqt; Cp = Qb;  sc = QSCALE; }
    else if (which == 1) { Ap = xb;  Bp = Wkt; Cp = Kb;  sc = 1.f; }
    else                 { Ap = Wvt; Bp = xb;  Cp = Vtb; sc = 1.f; }

#define STAGE_HALF(buf, type, kk, kb)                                                  \
    {                                                                                  \
        const u16* _src = (type) == 0 ? Ap : Bp;                                       \
        const int _b0 = (type) == 0 ? m0 : n0;                                         \
        u16* _dst = &lds[buf][type][kk][0];                                            \
        _Pragma("unroll") for (int _i = 0; _i < 2; _i++) {                             \
            int _s = _i * 512 + tid;                                                   \
            int _row = _s >> 2, _gr = _s & 3;                                          \
            int _sg = (_gr ^ (_row >> 1)) & 3;                                         \
            gld_lds16(_src + (size_t)(_b0 + _row) * 2048 + (kb) + (kk) * 32 + _sg * 8, \
                      _dst + _s * 8);                                                  \
        }                                                                              \
    }

    const f32x4 fzero = {0.f, 0.f, 0.f, 0.f};
    f32x4 acc[8][4];
#pragma unroll
    for (int m = 0; m < 8; m++)
#pragma unroll
        for (int n = 0; n < 4; n++) acc[m][n] = fzero;

    STAGE_HALF(0, 0, 0, 0);
    STAGE_HALF(0, 1, 0, 0);
    STAGE_HALF(0, 0, 1, 0);
    STAGE_HALF(0, 1, 1, 0);
    asm volatile("s_waitcnt vmcnt(4)" ::: "memory");
    __builtin_amdgcn_s_barrier();

    const int NT = 32;   // 2048 / 64
    for (int t = 0; t < NT; t++) {
        const int buf = t & 1, nbuf = buf ^ 1;
        const int kbn = (t + 1) * 64;
        const bool more = (t + 1 < NT);
        bf16x8 af[8];
#pragma unroll
        for (int p = 0; p < 4; p++) {
            const int kk = p >> 1, nh = p & 1;
            if (nh == 0) {
#pragma unroll
                for (int m = 0; m < 8; m++) {
                    int row = wm * 128 + m * 16 + q16;
                    af[m] = *(const bf16x8*)(&lds[buf][0][kk][row * 32 + 8 * ((g ^ (row >> 1)) & 3)]);
                }
            }
            bf16x8 bf0, bf1;
            {
                int rb0 = wn * 64 + (2 * nh + 0) * 16 + q16;
                int rb1 = wn * 64 + (2 * nh + 1) * 16 + q16;
                bf0 = *(const bf16x8*)(&lds[buf][1][kk][rb0 * 32 + 8 * ((g ^ (rb0 >> 1)) & 3)]);
                bf1 = *(const bf16x8*)(&lds[buf][1][kk][rb1 * 32 + 8 * ((g ^ (rb1 >> 1)) & 3)]);
            }
            if (more) {
                if (p == 0)      STAGE_HALF(nbuf, 0, 0, kbn)
                else if (p == 1) STAGE_HALF(nbuf, 1, 0, kbn)
                else if (p == 2) STAGE_HALF(nbuf, 0, 1, kbn)
                else             STAGE_HALF(nbuf, 1, 1, kbn)
            }
            __builtin_amdgcn_s_barrier();
            asm volatile("s_waitcnt lgkmcnt(0)" ::: "memory");
            __builtin_amdgcn_s_setprio(1);
#pragma unroll
            for (int m = 0; m < 8; m++) {
                acc[m][2 * nh + 0] = __builtin_amdgcn_mfma_f32_16x16x32_bf16(af[m], bf0, acc[m][2 * nh + 0], 0, 0, 0);
                acc[m][2 * nh + 1] = __builtin_amdgcn_mfma_f32_16x16x32_bf16(af[m], bf1, acc[m][2 * nh + 1], 0, 0, 0);
            }
            __builtin_amdgcn_s_setprio(0);
            if (p == 1) {
                if (more) asm volatile("s_waitcnt vmcnt(4)" ::: "memory");
                else      asm volatile("s_waitcnt vmcnt(0)" ::: "memory");
            } else if (p == 3) {
                asm volatile("s_waitcnt vmcnt(4)" ::: "memory");
            }
            __builtin_amdgcn_s_barrier();
        }
    }
#undef STAGE_HALF

#pragma unroll
    for (int m = 0; m < 8; m++)
#pragma unroll
        for (int n = 0; n < 4; n++) {
            int row = m0 + wm * 128 + m * 16 + 4 * g;
            int col = n0 + wn * 64 + n * 16 + q16;
#pragma unroll
            for (int rr = 0; rr < 4; rr++)
                Cp[(size_t)(row + rr) * 2048 + col] = f2bf(acc[m][n][rr] * sc);
        }
}

// ---------------- GEMM core (BK=64, 128x64): proven R8 core, for the f32-output projection ----------------
__device__ __forceinline__ void gemm_core64(const u16* __restrict__ A, const u16* __restrict__ B,
                                            float* __restrict__ Cout, float scale, int m0, int n0) {
    __shared__ __align__(16) u16 As[2][128 * 64];
    __shared__ __align__(16) u16 Bs[2][64 * 64];
    const int tid = threadIdx.x;
    const int lane = tid & 63, w = tid >> 6;
    const int q16 = lane & 15, g = lane >> 4;
    const int sw = q16 & 7;
    const f32x4 fzero = {0.f, 0.f, 0.f, 0.f};
    f32x4 acc[2][4];
#pragma unroll
    for (int m = 0; m < 2; m++)
#pragma unroll
        for (int n = 0; n < 4; n++) acc[m][n] = fzero;

#define STG64(buf, kb)                                                               \
    {                                                                                \
        _Pragma("unroll") for (int p = 0; p < 4; p++) {                              \
            int s = p * 256 + tid;  /* A: 1024 granules */                           \
            int row = s >> 3, sg = (s ^ row) & 7;                                    \
            gld_lds16(A + (size_t)(m0 + row) * 2048 + (kb) + sg * 8, As[buf] + s * 8); \
        }                                                                            \
        _Pragma("unroll") for (int p = 0; p < 2; p++) {                              \
            int s = p * 256 + tid;  /* B: 512 granules */                            \
            int row = s >> 3, sg = (s ^ row) & 7;                                    \
            gld_lds16(B + (size_t)(n0 + row) * 2048 + (kb) + sg * 8, Bs[buf] + s * 8); \
        }                                                                            \
    }

    STG64(0, 0);
    int cur = 0;
    for (int kb = 0; kb < 2048; kb += 64) {
        if (kb + 64 < 2048) {
            STG64(cur ^ 1, kb + 64);
            asm volatile("s_waitcnt vmcnt(6)" ::: "memory");
        } else {
            asm volatile("s_waitcnt vmcnt(0)" ::: "memory");
        }
        __builtin_amdgcn_s_barrier();
        bf16x8 af[2][2], bfr[4][2];
#pragma unroll
        for (int m = 0; m < 2; m++) {
            const u16* ar = As[cur] + (w * 32 + m * 16 + q16) * 64;
            af[m][0] = *(const bf16x8*)(ar + 8 * (g ^ sw));
            af[m][1] = *(const bf16x8*)(ar + 8 * ((4 + g) ^ sw));
        }
#pragma unroll
        for (int n = 0; n < 4; n++) {
            const u16* br = Bs[cur] + (n * 16 + q16) * 64;
            bfr[n][0] = *(const bf16x8*)(br + 8 * (g ^ sw));
            bfr[n][1] = *(const bf16x8*)(br + 8 * ((4 + g) ^ sw));
        }
        __builtin_amdgcn_s_setprio(1);
#pragma unroll
        for (int m = 0; m < 2; m++)
#pragma unroll
            for (int n = 0; n < 4; n++) {
                acc[m][n] = __builtin_amdgcn_mfma_f32_16x16x32_bf16(af[m][0], bfr[n][0], acc[m][n], 0, 0, 0);
                acc[m][n] = __builtin_amdgcn_mfma_f32_16x16x32_bf16(af[m][1], bfr[n][1], acc[m][n], 0, 0, 0);
            }
        __builtin_amdgcn_s_setprio(0);
        asm volatile("s_waitcnt lgkmcnt(0)" ::: "memory");
        __builtin_amdgcn_s_barrier();
        cur ^= 1;
    }
#pragma unroll
    for (int m = 0; m < 2; m++)
#pragma unroll
        for (int n = 0; n < 4; n++) {
            int row = m0 + w * 32 + m * 16 + 4 * g;
            int col = n0 + n * 16 + q16;
#pragma unroll
            for (int r = 0; r < 4; r++)
                Cout[(size_t)(row + r) * 2048 + col] = acc[m][n][r] * scale;
        }
#undef STG64
}

// final projection: 512 blocks (128x64 tiles)
__global__ __launch_bounds__(256, 3) void gemm_out(const u16* __restrict__ Mb, const u16* __restrict__ Wot,
                                                   float* __restrict__ out) {
    const int id = blockIdx.x;
    const int ord = (id & 7) * 64 + (id >> 3);
    const int m0 = (ord & 15) * 128, n0 = (ord >> 4) * 64;
    gemm_core64(Mb, Wot, out, 1.f, m0, n0);
}

// ---------------- fused dual-stream causal flash attention + diff + subLN + scatter to M ----------------
// grid 512 1D. Per-XCD balanced block remap ((A,33-A) size pairs -> 33 tile-iters per CU).
// No-max softmax (exp2 raw, bounded). K tile full 4-bit granule XOR swizzle. T14 V-hoist.
// R16 schedule restored: staging at loop top + counted vmcnt(8) (full-iteration cover —
// R17's stage-after-QK^T + vmcnt(0) drain had only ~400cy cover vs ~900cy HBM latency, -26us).
// Lambda via wave-parallel dot kept (loads at entry, butterfly in epilogue).
__global__ __launch_bounds__(256, 2) void diff_attn(const u16* __restrict__ Qg, const u16* __restrict__ Kg,
                                                    const u16* __restrict__ Vg, u16* __restrict__ Mg,
                                                    const float* __restrict__ lq1, const float* __restrict__ lk1,
                                                    const float* __restrict__ lq2, const float* __restrict__ lk2) {
    __shared__ __align__(16) u16 smem[40960];   // 80 KB -> 2 blocks/CU
    const int tid = threadIdx.x;
    const int lane = tid & 63, w = tid >> 6;
    const int q16 = lane & 15, g = lane >> 4;
    const int sw = q16 & 7;
    const int id = blockIdx.x;
    // balanced remap: XCD xcd, pair p, parity o. A(p) = 32-p (p<16) else p-15.
    const int xcd = id & 7, jj = id >> 3;
    const int p = jj >> 1, o = jj & 1;
    const int A = (p < 16) ? (32 - p) : (p - 15);
    const int s = o ? (33 - A) : A;   // tile count for this block, 1..32
    const int qi = s - 1;
    const int h = (xcd << 1) | o;
    const int q0 = qi * 64;
    const int qg = q0 + 16 * w + q16;

    // lambda partials: coalesced per-lane loads now, butterfly-reduced in the epilogue
    float la1 = lq1[lane] * lk1[lane];
    float la2 = lq2[lane] * lk2[lane];

    u16* Kb0 = smem;
    u16* Vb0 = smem + 8192;
    u16* Kb1 = smem + 16384;
    u16* Vb1 = smem + 24576;
    u16* Pw = smem + 32768 + w * 2048;  // [2 streams][16 q][64 k]

    bf16x8 qf[2][2];
#pragma unroll
    for (int st = 0; st < 2; st++)
#pragma unroll
        for (int db = 0; db < 2; db++)
            qf[st][db] = *(const bf16x8*)(Qg + (size_t)qg * 2048 + 128 * h + 64 * st + 32 * db + 8 * g);

// K: LDS slot gc (of row) holds global granule gc^(row&15); read granule j at slot j^(row&15)
#define STAGE_K(dst, kb)                                                         \
    {                                                                            \
        _Pragma("unroll") for (int p2 = 0; p2 < 4; p2++) {                       \
            int s2 = p2 * 256 + tid;                                             \
            int row = s2 >> 4, gc = s2 & 15;                                     \
            int sg = (gc ^ row) & 15;                                            \
            gld_lds16(Kg + (size_t)((kb) + row) * 2048 + 128 * h + sg * 8, (dst) + s2 * 8); \
        }                                                                        \
    }
#define STAGE_V(dst, kb)                                                         \
    {                                                                            \
        _Pragma("unroll") for (int p2 = 0; p2 < 4; p2++) {                       \
            int s2 = p2 * 256 + tid;                                             \
            int row = s2 >> 3, sg = (s2 ^ row) & 7;                              \
            gld_lds16(Vg + (size_t)(128 * h + row) * 2048 + (kb) + sg * 8, (dst) + s2 * 8); \
        }                                                                        \
    }

    const f32x4 fzero = {0.f, 0.f, 0.f, 0.f};
    f32x4 Oacc[2][8];
#pragma unroll
    for (int st = 0; st < 2; st++)
#pragma unroll
        for (int dt = 0; dt < 8; dt++) Oacc[st][dt] = fzero;
    float den[2] = {0.f, 0.f};   // per-lane partial denominators; reduced in epilogue

    const int nt = qi + 1;
    STAGE_K(Kb0, 0);
    STAGE_V(Vb0, 0);
    int cur = 0;
    for (int t = 0; t < nt; t++) {
        const int kb = t * 64;
        const u16* Ks = cur ? Kb1 : Kb0;
        const u16* Vs = cur ? Vb1 : Vb0;
        if (t + 1 < nt) {
            STAGE_K(cur ? Kb0 : Kb1, kb + 64);
            STAGE_V(cur ? Vb0 : Vb1, kb + 64);
            asm volatile("s_waitcnt vmcnt(8)" ::: "memory");
        } else {
            asm volatile("s_waitcnt vmcnt(0)" ::: "memory");
        }
        __builtin_amdgcn_s_barrier();

        // T14: issue ALL V-fragment reads now; they retire under QK^T + softmax.
        bf16x8 vfr[2][8];
#pragma unroll
        for (int kh = 0; kh < 2; kh++)
#pragma unroll
            for (int dt = 0; dt < 8; dt++)
                vfr[kh][dt] = *(const bf16x8*)(Vs + (dt * 16 + q16) * 64 + 8 * ((kh * 4 + g) ^ sw));

        // QK^T (S^T): D[k][q], both streams; K slots XOR-swizzled by q16
        f32x4 sc[2][4];
        __builtin_amdgcn_s_setprio(1);
#pragma unroll
        for (int st = 0; st < 2; st++)
#pragma unroll
            for (int kt = 0; kt < 4; kt++) {
                const u16* kr = Ks + (kt * 16 + q16) * 128;
                bf16x8 kf0 = *(const bf16x8*)(kr + 8 * ((st * 8 + g) ^ q16));
                bf16x8 kf1 = *(const bf16x8*)(kr + 8 * ((st * 8 + 4 + g) ^ q16));
                f32x4 a = __builtin_amdgcn_mfma_f32_16x16x32_bf16(kf0, qf[st][0], fzero, 0, 0, 0);
                a = __builtin_amdgcn_mfma_f32_16x16x32_bf16(kf1, qf[st][1], a, 0, 0, 0);
                sc[st][kt] = a;
            }
        __builtin_amdgcn_s_setprio(0);

        const bool last = (t == nt - 1);
        // no-max softmax: P = exp2(S) raw (bounded), mask via select-to-zero on diag tile
#pragma unroll
        for (int st = 0; st < 2; st++) {
            u16* Pst = Pw + st * 1024;
            float dl = 0.f;
#pragma unroll
            for (int kt = 0; kt < 4; kt++) {
                float p0 = EXP2F(sc[st][kt][0]);
                float p1 = EXP2F(sc[st][kt][1]);
                float p2 = EXP2F(sc[st][kt][2]);
                float p3 = EXP2F(sc[st][kt][3]);
                if (last) {
                    const int kgi = kb + kt * 16 + 4 * g;
                    p0 = (kgi + 0 <= qg) ? p0 : 0.f;
                    p1 = (kgi + 1 <= qg) ? p1 : 0.f;
                    p2 = (kgi + 2 <= qg) ? p2 : 0.f;
                    p3 = (kgi + 3 <= qg) ? p3 : 0.f;
                }
                dl += (p0 + p1) + (p2 + p3);
                uint2 pr;
                pr.x = pkbf(p0, p1);
                pr.y = pkbf(p2, p3);
                *(uint2*)(Pst + q16 * 64 + ((kt * 16 + 4 * g) ^ (8 * sw))) = pr;
            }
            den[st] += dl;
        }

        // PV: O^T = V^T x P^T ; V fragments already in registers
        bf16x8 pf[2][2];
#pragma unroll
        for (int st = 0; st < 2; st++)
#pragma unroll
            for (int kh = 0; kh < 2; kh++)
                pf[st][kh] = *(const bf16x8*)(Pw + st * 1024 + q16 * 64 + ((kh * 32 + 8 * g) ^ (8 * sw)));
        __builtin_amdgcn_s_setprio(1);
#pragma unroll
        for (int kh = 0; kh < 2; kh++)
#pragma unroll
            for (int dt = 0; dt < 8; dt++) {
                Oacc[0][dt] = __builtin_amdgcn_mfma_f32_16x16x32_bf16(vfr[kh][dt], pf[0][kh], Oacc[0][dt], 0, 0, 0);
                Oacc[1][dt] = __builtin_amdgcn_mfma_f32_16x16x32_bf16(vfr[kh][dt], pf[1][kh], Oacc[1][dt], 0, 0, 0);
            }
        __builtin_amdgcn_s_setprio(0);
        asm volatile("s_waitcnt lgkmcnt(0)" ::: "memory");
        __builtin_amdgcn_s_barrier();
        cur ^= 1;
    }
#undef STAGE_K
#undef STAGE_V

    // lambda: butterfly-reduce the per-lane partials across all 64 lanes
#pragma unroll
    for (int m = 1; m < 64; m <<= 1) {
        la1 += __shfl_xor(la1, m);
        la2 += __shfl_xor(la2, m);
    }
    const float lam = expf(la1) - expf(la2) + LAMBDA_INIT;

    // epilogue: reduce denominators across the 4-lane q-group, diff, LN over 128 dims, M write
    float d0 = den[0], d1 = den[1];
    d0 += __shfl_xor(d0, 16); d0 += __shfl_xor(d0, 32);
    d1 += __shfl_xor(d1, 16); d1 += __shfl_xor(d1, 32);
    const float i1 = 1.f / d0;
    const float i2 = lam / d1;
    float S1 = 0.f, S2 = 0.f;
#pragma unroll
    for (int dt = 0; dt < 8; dt++)
#pragma unroll
        for (int r = 0; r < 4; r++) {
            float v = Oacc[0][dt][r] * i1 - Oacc[1][dt][r] * i2;
            S1 += v; S2 += v * v;
        }
    S1 += __shfl_xor(S1, 16); S1 += __shfl_xor(S1, 32);
    S2 += __shfl_xor(S2, 16); S2 += __shfl_xor(S2, 32);
    const float mu = S1 * (1.f / 128.f);
    const float var = S2 * (1.f / 128.f) - mu * mu;
    const float rs = rsqrtf(var + 1e-5f) * ONE_MINUS_LI;

    const int R = h * 128 + (q0 >> 4) + w;  // same for whole wave
    u16* drow = Mg + (size_t)R * 2048 + q16 * 128;
#pragma unroll
    for (int dt = 0; dt < 8; dt++) {
        float v0 = (Oacc[0][dt][0] * i1 - Oacc[1][dt][0] * i2 - mu) * rs;
        float v1 = (Oacc[0][dt][1] * i1 - Oacc[1][dt][1] * i2 - mu) * rs;
        float v2 = (Oacc[0][dt][2] * i1 - Oacc[1][dt][2] * i2 - mu) * rs;
        float v3 = (Oacc[0][dt][3] * i1 - Oacc[1][dt][3] * i2 - mu) * rs;
        uint2 oo;
        oo.x = pkbf(v0, v1);
        oo.y = pkbf(v2, v3);
        *(uint2*)(drow + dt * 16 + 4 * g) = oo;
    }
}

extern "C" void kernel_launch(void* const* d_in, const int* in_sizes, int n_in,
                              void* d_out, int out_size, void* d_ws, size_t ws_size,
                              hipStream_t stream) {
    (void)in_sizes; (void)n_in; (void)out_size; (void)ws_size;
    const float* x = (const float*)d_in[0];
    const float* Wq = (const float*)d_in[1];
    const float* Wk = (const float*)d_in[2];
    const float* Wv = (const float*)d_in[3];
    const float* Wo = (const float*)d_in[4];
    const float* lq1 = (const float*)d_in[5];
    const float* lk1 = (const float*)d_in[6];
    const float* lq2 = (const float*)d_in[7];
    const float* lk2 = (const float*)d_in[8];

    u16* ws = (u16*)d_ws;
    const size_t SZ = 2048u * 2048u;
    u16* xb = ws;
    u16* Wqt = ws + SZ;
    u16* Wkt = ws + 2 * SZ;
    u16* Wvt = ws + 3 * SZ;
    u16* Wot = ws + 4 * SZ;
    u16* Qb = ws + 5 * SZ;
    u16* Kb = ws + 6 * SZ;
    u16* Vtb = ws + 7 * SZ;
    u16* Mb = ws + 8 * SZ;

    prep_inputs<<<dim3(32, 32, 5), 256, 0, stream>>>(x, Wq, Wk, Wv, Wo, xb, Wqt, Wkt, Wvt, Wot);

    gemm_qkv<<<192, 512, 0, stream>>>(xb, Wqt, Wkt, Wvt, Qb, Kb, Vtb);

    diff_attn<<<512, 256, 0, stream>>>(Qb, Kb, Vtb, Mb, lq1, lk1, lq2, lk2);

    gemm_out<<<512, 256, 0, stream>>>(Mb, Wot, (float*)d_out);
}